// Round 3
// baseline (364.939 us; speedup 1.0000x reference)
//
#include <hip/hip_runtime.h>
#include <hip/hip_cooperative_groups.h>

namespace cg = cooperative_groups;

#define EMA_EPS 1e-12f
#define RPB 64         // rows per block in the cooperative kernel
#define TS  64         // s-rows per block in the fallback scan+norm kernel

typedef float v4f __attribute__((ext_vector_type(4)));

__device__ __forceinline__ float wave_reduce_sum(float v) {
    #pragma unroll
    for (int off = 32; off > 0; off >>= 1) v += __shfl_xor(v, off, 64);
    return v;
}

// ---------------------------------------------------------------------------
// Cooperative single-launch kernel (D == 512, S % 64 == 0).
// Block bid owns rows [bid*64, bid*64+64) = batch b = bid/(S/64), seg sg.
// Phase 1: per-row weighted stats (w_t = (1-a)a^t premultiplied) + in-LDS
//          64-row inclusive scan; publish segment totals.
// grid.sync()
// Phase 2: one wave redundantly sums the <=127 predecessor segment totals
//          (512 KB array, L2-resident) -> exclusive prefix. No spin locks.
// Phase 3: normalize the block's 64 rows; x re-read is L3-warm (128 MiB of
//          x fits the 256 MiB L3); y uses non-temporal stores to not evict x.
// ---------------------------------------------------------------------------
__global__ __launch_bounds__(256, 4) void ema_coop_kernel(
    const float* __restrict__ x,
    const float* __restrict__ h, const float* __restrict__ alpha_logit,
    const float* __restrict__ gamma, const float* __restrict__ beta,
    float* __restrict__ out,
    float* __restrict__ segM, float* __restrict__ segS,
    int B, int S)
{
    const int SEG  = S / RPB;
    const int bid  = (int)blockIdx.x;
    const int b    = bid / SEG;
    const int sg   = bid % SEG;
    const int tid  = (int)threadIdx.x;
    const int lane = tid & 63;
    const int wv   = tid >> 6;

    __shared__ float sh_m[RPB], sh_s[RPB];
    __shared__ float sh_ex[2];

    const float alpha = 1.0f / (1.0f + __expf(-alpha_logit[0]));
    const float oma   = 1.0f - alpha;
    const float l2a   = __log2f(alpha);

    const int t0 = sg * RPB;                       // row index within batch
    const float4* xb = (const float4*)x + (size_t)bid * RPB * 128;

    // ---- Phase 1: wave wv handles rows wv*16 .. wv*16+15 (2 rows in flight)
    #pragma unroll
    for (int k = 0; k < 16; k += 2) {
        const int r0 = wv * 16 + k;
        const float4* x0 = xb + (size_t)r0 * 128;
        const float4* x1 = x0 + 128;
        float4 a0 = x0[lane], c0 = x0[lane + 64];
        float4 a1 = x1[lane], c1 = x1[lane + 64];
        float s0 = a0.x + a0.y + a0.z + a0.w + c0.x + c0.y + c0.z + c0.w;
        float q0 = a0.x*a0.x + a0.y*a0.y + a0.z*a0.z + a0.w*a0.w
                 + c0.x*c0.x + c0.y*c0.y + c0.z*c0.z + c0.w*c0.w;
        float s1 = a1.x + a1.y + a1.z + a1.w + c1.x + c1.y + c1.z + c1.w;
        float q1 = a1.x*a1.x + a1.y*a1.y + a1.z*a1.z + a1.w*a1.w
                 + c1.x*c1.x + c1.y*c1.y + c1.z*c1.z + c1.w*c1.w;
        s0 = wave_reduce_sum(s0); q0 = wave_reduce_sum(q0);
        s1 = wave_reduce_sum(s1); q1 = wave_reduce_sum(q1);
        if (lane == 0) {
            float mean0 = s0 * (1.0f / 512.0f);
            float var0  = (q0 - s0 * mean0) * (1.0f / 511.0f);
            float sd0   = sqrtf(fmaxf(var0, 0.0f));
            float w0    = oma * exp2f((float)(t0 + r0) * l2a);
            sh_m[r0]    = w0 * mean0;
            sh_s[r0]    = w0 * sd0;
            float mean1 = s1 * (1.0f / 512.0f);
            float var1  = (q1 - s1 * mean1) * (1.0f / 511.0f);
            float sd1   = sqrtf(fmaxf(var1, 0.0f));
            float w1    = oma * exp2f((float)(t0 + r0 + 1) * l2a);
            sh_m[r0+1]  = w1 * mean1;
            sh_s[r0+1]  = w1 * sd1;
        }
    }
    __syncthreads();

    // ---- Phase 1b: wave 0 scans the 64 in-tile rows, publishes segment total
    if (wv == 0) {
        float vm = sh_m[lane], vs = sh_s[lane];
        #pragma unroll
        for (int off = 1; off < 64; off <<= 1) {
            float tm = __shfl_up(vm, off, 64);
            float tv = __shfl_up(vs, off, 64);
            if (lane >= off) { vm += tm; vs += tv; }
        }
        sh_m[lane] = vm; sh_s[lane] = vs;
        if (lane == 63) { segM[bid] = vm; segS[bid] = vs; }
    }

    cg::this_grid().sync();

    // ---- Phase 2: exclusive prefix over predecessor segments of this batch
    if (wv == 0) {
        float em = 0.f, es = 0.f;
        for (int k = lane; k < sg; k += 64) {
            em += segM[b * SEG + k];
            es += segS[b * SEG + k];
        }
        em = wave_reduce_sum(em);
        es = wave_reduce_sum(es);
        if (lane == 0) {
            sh_ex[0] = alpha * h[2*b + 0] + em;
            sh_ex[1] = alpha * h[2*b + 1] + es;
        }
    }
    __syncthreads();

    // ---- Phase 2b: finalize per-row mu and 1/sigma (one divide per row)
    if (tid < RPB) {
        float m  = sh_ex[0] + sh_m[tid];
        float sd = fmaxf(sh_ex[1] + sh_s[tid], EMA_EPS);
        sh_m[tid] = m;
        sh_s[tid] = 1.0f / sd;
        if (sg == SEG - 1 && tid == RPB - 1) {
            float* h_new = out + (size_t)B * S * 512;
            h_new[2*b + 0] = m;
            h_new[2*b + 1] = sd;
        }
    }
    __syncthreads();

    // ---- Phase 3: normalize (x L3-warm) + non-temporal store of y
    const float4* g4 = (const float4*)gamma;
    const float4* b4 = (const float4*)beta;
    v4f* yb = (v4f*)out + (size_t)bid * RPB * 128;
    #pragma unroll 4
    for (int i = tid; i < RPB * 128; i += 256) {
        const int r = i >> 7;
        const int c = i & 127;
        const float m  = sh_m[r];
        const float rs = sh_s[r];
        float4 xv = xb[i];
        float4 g  = g4[c];
        float4 bt = b4[c];
        v4f yv;
        yv.x = (xv.x - m) * rs * g.x + bt.x;
        yv.y = (xv.y - m) * rs * g.y + bt.y;
        yv.z = (xv.z - m) * rs * g.z + bt.z;
        yv.w = (xv.w - m) * rs * g.w + bt.w;
        __builtin_nontemporal_store(yv, &yb[i]);
    }
}

// ---------------------------------------------------------------------------
// Fallback path: the proven round-0 two-kernel structure (any shape).
// ---------------------------------------------------------------------------
__global__ __launch_bounds__(256) void ema_stats_kernel(
    const float* __restrict__ x,
    float* __restrict__ mu, float* __restrict__ sigma,
    int nrows, int d4)
{
    int row  = (int)((blockIdx.x * blockDim.x + threadIdx.x) >> 6);
    int lane = threadIdx.x & 63;
    if (row >= nrows) return;

    const float4* xr = (const float4*)(x + (size_t)row * (size_t)(d4 * 4));
    float s = 0.f, sq = 0.f;
    for (int c = lane; c < d4; c += 64) {
        float4 a = xr[c];
        s  += a.x + a.y + a.z + a.w;
        sq += a.x*a.x + a.y*a.y + a.z*a.z + a.w*a.w;
    }
    s  = wave_reduce_sum(s);
    sq = wave_reduce_sum(sq);
    if (lane == 0) {
        int   n    = d4 * 4;
        float mean = s / (float)n;
        float var  = (sq - s * mean) / (float)(n - 1);
        mu[row]    = mean;
        sigma[row] = sqrtf(fmaxf(var, 0.0f));
    }
}

__global__ __launch_bounds__(256) void ema_scan_norm_kernel(
    const float* __restrict__ x,
    const float* __restrict__ mu, const float* __restrict__ sigma,
    const float* __restrict__ h, const float* __restrict__ alpha_logit,
    const float* __restrict__ gamma, const float* __restrict__ beta,
    float* __restrict__ out, int B, int S, int d4_shift)
{
    const int tiles = S / TS;
    const int b     = (int)blockIdx.x / tiles;
    const int tile  = (int)blockIdx.x % tiles;
    const int s0    = tile * TS;
    const int tid   = threadIdx.x;
    const int d4    = 1 << d4_shift;
    const int D     = d4 << 2;

    const float alpha = 1.0f / (1.0f + __expf(-alpha_logit[0]));
    const float oma   = 1.0f - alpha;
    const float l2a   = __log2f(alpha);

    const float* mub = mu    + (size_t)b * S;
    const float* sgb = sigma + (size_t)b * S;

    __shared__ float sh_wm[4], sh_ws[4];
    __shared__ float sh_pm, sh_ps;
    __shared__ float sh_m[TS], sh_r[TS];

    float lm = 0.f, ls = 0.f;
    for (int t = tid; t < s0; t += 256) {
        float w = oma * exp2f((float)t * l2a);
        lm += w * mub[t];
        ls += w * sgb[t];
    }
    lm = wave_reduce_sum(lm);
    ls = wave_reduce_sum(ls);
    if ((tid & 63) == 0) { sh_wm[tid >> 6] = lm; sh_ws[tid >> 6] = ls; }
    __syncthreads();
    if (tid == 0) {
        sh_pm = sh_wm[0] + sh_wm[1] + sh_wm[2] + sh_wm[3];
        sh_ps = sh_ws[0] + sh_ws[1] + sh_ws[2] + sh_ws[3];
    }
    __syncthreads();

    if (tid < 64) {
        const int lane = tid;
        float w  = oma * exp2f((float)(s0 + lane) * l2a);
        float vm = w * mub[s0 + lane];
        float vs = w * sgb[s0 + lane];
        #pragma unroll
        for (int off = 1; off < 64; off <<= 1) {
            float tm = __shfl_up(vm, off, 64);
            float tv = __shfl_up(vs, off, 64);
            if (lane >= off) { vm += tm; vs += tv; }
        }
        float run_m = alpha * h[b * 2 + 0] + sh_pm + vm;
        float run_s = fmaxf(alpha * h[b * 2 + 1] + sh_ps + vs, EMA_EPS);
        sh_m[lane] = run_m;
        sh_r[lane] = 1.0f / run_s;
        if (s0 + TS == S && lane == 63) {
            float* h_new = out + (size_t)B * S * D;
            h_new[b * 2 + 0] = run_m;
            h_new[b * 2 + 1] = run_s;
        }
    }
    __syncthreads();

    const size_t base = (size_t)(b * S + s0) << d4_shift;
    const float4* xb = (const float4*)x + base;
    float4*       yb = (float4*)out + base;
    const float4* g4 = (const float4*)gamma;
    const float4* b4 = (const float4*)beta;
    const int n4 = TS << d4_shift;
    for (int i = tid; i < n4; i += 256) {
        int r = i >> d4_shift;
        int c = i & (d4 - 1);
        float m  = sh_m[r];
        float rs = sh_r[r];
        float4 g  = g4[c];
        float4 bt = b4[c];
        float4 xv = xb[i];
        float4 yv;
        yv.x = (xv.x - m) * rs * g.x + bt.x;
        yv.y = (xv.y - m) * rs * g.y + bt.y;
        yv.z = (xv.z - m) * rs * g.z + bt.z;
        yv.w = (xv.w - m) * rs * g.w + bt.w;
        yb[i] = yv;
    }
}

extern "C" void kernel_launch(void* const* d_in, const int* in_sizes, int n_in,
                              void* d_out, int out_size, void* d_ws, size_t ws_size,
                              hipStream_t stream) {
    const float* x           = (const float*)d_in[0];
    const float* h           = (const float*)d_in[1];
    const float* gamma       = (const float*)d_in[2];
    const float* beta        = (const float*)d_in[3];
    const float* alpha_logit = (const float*)d_in[4];
    float* out = (float*)d_out;

    const int D     = in_sizes[2];          // 512
    const int B     = in_sizes[1] / 2;      // 8
    const int total = in_sizes[0];          // B*S*D
    const int S     = total / (B * D);      // 8192
    const int nrows = B * S;

    if (D == 512 && (S % RPB) == 0) {
        const int grid = nrows / RPB;       // 1024

        // one-time co-residency check for the cooperative launch
        static int coop_capacity = -1;
        if (coop_capacity < 0) {
            int dev = 0;
            hipGetDevice(&dev);
            hipDeviceProp_t prop;
            hipGetDeviceProperties(&prop, dev);
            int nb = 0;
            hipOccupancyMaxActiveBlocksPerMultiprocessor(&nb, ema_coop_kernel, 256, 0);
            coop_capacity = nb * prop.multiProcessorCount;
        }

        if (grid <= coop_capacity) {
            float* segM = (float*)d_ws;
            float* segS = segM + grid;
            int Bv = B, Sv = S;
            void* args[] = {(void*)&x, (void*)&h, (void*)&alpha_logit,
                            (void*)&gamma, (void*)&beta, (void*)&out,
                            (void*)&segM, (void*)&segS, (void*)&Bv, (void*)&Sv};
            hipError_t e = hipLaunchCooperativeKernel((void*)ema_coop_kernel,
                                                      dim3(grid), dim3(256),
                                                      args, 0, stream);
            if (e == hipSuccess) return;
            // launch rejected (capture/co-residency) -> fall through to fallback
        }
    }

    // --- fallback: proven two-kernel path ---
    const int d4 = D / 4;
    const int d4_shift = __builtin_ctz(d4);
    float* mu_ws = (float*)d_ws;
    float* sg_ws = mu_ws + nrows;
    ema_stats_kernel<<<(nrows + 3) / 4, 256, 0, stream>>>(x, mu_ws, sg_ws, nrows, d4);
    ema_scan_norm_kernel<<<B * (S / TS), 256, 0, stream>>>(
        x, mu_ws, sg_ws, h, alpha_logit, gamma, beta, out, B, S, d4_shift);
}

// Round 4
// 246.813 us; speedup vs baseline: 1.4786x; 1.4786x over previous
//
#include <hip/hip_runtime.h>

#define EMA_EPS 1e-12f
#define WTHR    1e-12f   // weight threshold: w_t below this cannot affect fp32 result
#define TS      32       // s-rows per block in the scan+norm kernel

typedef float v4f __attribute__((ext_vector_type(4)));

__device__ __forceinline__ float wave_reduce_sum(float v) {
    #pragma unroll
    for (int off = 32; off > 0; off >>= 1) v += __shfl_xor(v, off, 64);
    return v;
}

// Rows with index >= cut(alpha) have w_t = (1-a)a^t < WTHR -> contribute 0.
// Same formula used in both kernels; +2 margin absorbs fp32 slop.
__device__ __forceinline__ int decay_cutoff(float oma, float l2a, int S) {
    int cut = S;
    if (oma > 0.0f && l2a < -1e-20f) {
        // log2(1e-12) = -39.863137
        float tc = (-39.863137f - __log2f(oma)) / l2a;
        if (tc < 0.0f)          cut = 0;
        else if (tc < (float)S) cut = (int)tc + 2;
    }
    return cut;
}

// ---------------------------------------------------------------------------
// K1: per-row mean/std (ddof=1) premultiplied by w_t = (1-a)*a^t.
// One 64-lane wave per row. Rows past the decay cutoff skip the x read
// entirely and write exact zeros (keeps workspace poison-free so K2 can
// read every row unconditionally).
// ---------------------------------------------------------------------------
__global__ __launch_bounds__(256) void ema_stats_kernel(
    const float* __restrict__ x,
    float* __restrict__ wm, float* __restrict__ wsg,
    const float* __restrict__ alpha_logit,
    int nrows, int S, int d4)
{
    const int row  = (int)((blockIdx.x * blockDim.x + threadIdx.x) >> 6);
    const int lane = threadIdx.x & 63;
    if (row >= nrows) return;

    const float alpha = 1.0f / (1.0f + __expf(-alpha_logit[0]));
    const float oma   = 1.0f - alpha;
    const float l2a   = __log2f(alpha);
    const int   t     = row % S;
    const float w     = oma * exp2f((float)t * l2a);

    if (!(w >= WTHR)) {                 // also catches w==0 / denormal
        if (lane == 0) { wm[row] = 0.0f; wsg[row] = 0.0f; }
        return;
    }

    const float4* xr = (const float4*)x + (size_t)row * d4;
    float s = 0.f, sq = 0.f;
    for (int c = lane; c < d4; c += 64) {
        float4 a = xr[c];
        s  += a.x + a.y + a.z + a.w;
        sq += a.x*a.x + a.y*a.y + a.z*a.z + a.w*a.w;
    }
    s  = wave_reduce_sum(s);
    sq = wave_reduce_sum(sq);
    if (lane == 0) {
        const int n  = d4 * 4;
        float mean = s / (float)n;
        float var  = (sq - s * mean) / (float)(n - 1);
        float sd   = sqrtf(fmaxf(var, 0.0f));
        wm[row]  = w * mean;
        wsg[row] = w * sd;
    }
}

// ---------------------------------------------------------------------------
// K2: fused prefix-reduce + tile-scan + normalize. Block (b, tile) owns rows
// [s0, s0+TS). Phase A redundantly sums the weighted prefix over
// [0, min(s0, cut)) — pure adds over L2-resident data (no exp2f, truncated
// at the decay cutoff). Phase B: wave 0 scans mu in lanes 0-31 and sigma in
// lanes 32-63 (width-32 shuffles). Phase C: streaming normalize with
// non-temporal stores.
// ---------------------------------------------------------------------------
__global__ __launch_bounds__(256) void ema_scan_norm_kernel(
    const float* __restrict__ x,
    const float* __restrict__ wm, const float* __restrict__ wsg,
    const float* __restrict__ h, const float* __restrict__ alpha_logit,
    const float* __restrict__ gamma, const float* __restrict__ beta,
    float* __restrict__ out, int B, int S, int d4_shift)
{
    const int tiles = S / TS;
    const int b     = (int)blockIdx.x / tiles;
    const int tile  = (int)blockIdx.x % tiles;
    const int s0    = tile * TS;
    const int tid   = (int)threadIdx.x;
    const int d4    = 1 << d4_shift;
    const int D     = d4 << 2;

    const float alpha = 1.0f / (1.0f + __expf(-alpha_logit[0]));
    const float oma   = 1.0f - alpha;
    const float l2a   = __log2f(alpha);
    const int   cut   = decay_cutoff(oma, l2a, S);

    const float* wmb = wm  + (size_t)b * S;
    const float* wsb = wsg + (size_t)b * S;

    __shared__ float sh_wm[4], sh_ws[4];
    __shared__ float sh_pm, sh_ps;
    __shared__ float sh_m[TS], sh_r[TS];

    // ---- Phase A: truncated weighted-prefix reduction over [0, min(s0,cut))
    const int m0 = (s0 < cut) ? s0 : cut;
    float lm = 0.f, ls = 0.f;
    for (int t = tid; t < m0; t += 256) {
        lm += wmb[t];
        ls += wsb[t];
    }
    lm = wave_reduce_sum(lm);
    ls = wave_reduce_sum(ls);
    if ((tid & 63) == 0) { sh_wm[tid >> 6] = lm; sh_ws[tid >> 6] = ls; }
    __syncthreads();
    if (tid == 0) {
        sh_pm = sh_wm[0] + sh_wm[1] + sh_wm[2] + sh_wm[3];
        sh_ps = sh_ws[0] + sh_ws[1] + sh_ws[2] + sh_ws[3];
    }
    __syncthreads();

    // ---- Phase B: wave 0 dual 32-lane scans (mu in lanes 0-31, sigma 32-63)
    if (tid < 64) {
        const int  r   = tid & 31;
        const bool isM = tid < 32;
        float v = isM ? wmb[s0 + r] : wsb[s0 + r];
        #pragma unroll
        for (int off = 1; off < 32; off <<= 1) {
            float tv = __shfl_up(v, off, 32);
            if (r >= off) v += tv;
        }
        const float base = isM ? (alpha * h[b*2 + 0] + sh_pm)
                               : (alpha * h[b*2 + 1] + sh_ps);
        const float run = base + v;
        if (isM) sh_m[r] = run;
        else     sh_r[r] = 1.0f / fmaxf(run, EMA_EPS);
        if (s0 + TS == S && r == 31) {
            float* h_new = out + (size_t)B * S * D;
            if (isM) h_new[b*2 + 0] = run;
            else     h_new[b*2 + 1] = fmaxf(run, EMA_EPS);
        }
    }
    __syncthreads();

    // ---- Phase C: streaming normalize + non-temporal stores
    const size_t base = (size_t)(b * S + s0) << d4_shift;
    const float4* xb = (const float4*)x + base;
    v4f*          yb = (v4f*)out + base;
    const float4* g4 = (const float4*)gamma;
    const float4* b4 = (const float4*)beta;
    const int n4 = TS << d4_shift;
    #pragma unroll 4
    for (int i = tid; i < n4; i += 256) {
        const int r = i >> d4_shift;
        const int c = i & (d4 - 1);
        const float m  = sh_m[r];
        const float rs = sh_r[r];
        float4 g  = g4[c];
        float4 bt = b4[c];
        float4 xv = xb[i];
        v4f yv;
        yv.x = (xv.x - m) * rs * g.x + bt.x;
        yv.y = (xv.y - m) * rs * g.y + bt.y;
        yv.z = (xv.z - m) * rs * g.z + bt.z;
        yv.w = (xv.w - m) * rs * g.w + bt.w;
        __builtin_nontemporal_store(yv, &yb[i]);
    }
}

extern "C" void kernel_launch(void* const* d_in, const int* in_sizes, int n_in,
                              void* d_out, int out_size, void* d_ws, size_t ws_size,
                              hipStream_t stream) {
    const float* x           = (const float*)d_in[0];
    const float* h           = (const float*)d_in[1];
    const float* gamma       = (const float*)d_in[2];
    const float* beta        = (const float*)d_in[3];
    const float* alpha_logit = (const float*)d_in[4];
    float* out = (float*)d_out;

    const int D     = in_sizes[2];          // 512
    const int B     = in_sizes[1] / 2;      // 8
    const int total = in_sizes[0];          // B*S*D
    const int S     = total / (B * D);      // 8192
    const int nrows = B * S;
    const int d4    = D / 4;
    const int d4_shift = __builtin_ctz(d4);

    float* wm_ws = (float*)d_ws;
    float* sg_ws = wm_ws + nrows;

    // K1: weighted stats; rows past the decay cutoff skip the x read.
    ema_stats_kernel<<<(nrows + 3) / 4, 256, 0, stream>>>(
        x, wm_ws, sg_ws, alpha_logit, nrows, S, d4);

    // K2: fused truncated-prefix + dual-scan + streaming normalize.
    ema_scan_norm_kernel<<<B * (S / TS), 256, 0, stream>>>(
        x, wm_ws, sg_ws, h, alpha_logit, gamma, beta, out, B, S, d4_shift);
}

// Round 6
// 241.118 us; speedup vs baseline: 1.5135x; 1.0236x over previous
//
#include <hip/hip_runtime.h>

#define EMA_EPS 1e-12f
#define WTHR    1e-12f   // weight threshold: w_t below this cannot affect fp32 result
#define TS      32       // s-rows per block in the scan+norm kernel

typedef float v4f __attribute__((ext_vector_type(4)));

__device__ __forceinline__ float wave_reduce_sum(float v) {
    #pragma unroll
    for (int off = 32; off > 0; off >>= 1) v += __shfl_xor(v, off, 64);
    return v;
}

// Rows with index >= cut(alpha) have w_t = (1-a)a^t < WTHR -> contribute 0.
// IDENTICAL formula in K1 and K2 so the skip-set and the guard-set match
// exactly (K1 never writes a row that K2 reads, and vice versa).
__device__ __forceinline__ int decay_cutoff(float oma, float l2a, int S) {
    int cut = S;
    if (oma > 0.0f && l2a < -1e-20f) {
        // log2(1e-12) = -39.863137
        float tc = (-39.863137f - __log2f(oma)) / l2a;
        if (tc < 0.0f)          cut = 0;
        else if (tc < (float)S) cut = (int)tc + 2;
    }
    return cut;
}

// ---------------------------------------------------------------------------
// K1: per-row mean/std (ddof=1) premultiplied by w_t = (1-a)*a^t.
// One 64-lane wave per row. Rows with t >= cut return immediately WITHOUT
// writing (K2 zero-guards them), so K1 touches only ~cut/S of x and nothing
// else. Normal (cached) loads on purpose: leaves these rows L3-resident for
// K2's re-read.
// ---------------------------------------------------------------------------
__global__ __launch_bounds__(256) void ema_stats_kernel(
    const float* __restrict__ x,
    float* __restrict__ wm, float* __restrict__ wsg,
    const float* __restrict__ alpha_logit,
    int nrows, int S, int d4)
{
    const int row  = (int)((blockIdx.x * blockDim.x + threadIdx.x) >> 6);
    const int lane = threadIdx.x & 63;
    if (row >= nrows) return;

    const float alpha = 1.0f / (1.0f + __expf(-alpha_logit[0]));
    const float oma   = 1.0f - alpha;
    const float l2a   = __log2f(alpha);
    const int   cut   = decay_cutoff(oma, l2a, S);
    const int   t     = row % S;
    if (t >= cut) return;               // K2 guards these rows to exact zero

    const float w = oma * exp2f((float)t * l2a);

    const float4* xr = (const float4*)x + (size_t)row * d4;
    float s = 0.f, sq = 0.f;
    for (int c = lane; c < d4; c += 64) {
        float4 a = xr[c];
        s  += a.x + a.y + a.z + a.w;
        sq += a.x*a.x + a.y*a.y + a.z*a.z + a.w*a.w;
    }
    s  = wave_reduce_sum(s);
    sq = wave_reduce_sum(sq);
    if (lane == 0) {
        const int n  = d4 * 4;
        float mean = s / (float)n;
        float var  = (sq - s * mean) / (float)(n - 1);
        float sd   = sqrtf(fmaxf(var, 0.0f));
        wm[row]  = w * mean;
        wsg[row] = w * sd;
    }
}

// ---------------------------------------------------------------------------
// K2: fused prefix-reduce + tile-scan + normalize. Block (b, tile) owns rows
// [s0, s0+TS). Phase A redundantly sums the weighted prefix over
// [0, min(s0, cut)) — pure adds over L2-resident data. Phase B: wave 0 scans
// mu in lanes 0-31 and sigma in lanes 32-63 (width-32 shuffles), zero-guarding
// rows past the decay cutoff. Phase C: streaming normalize, non-temporal x
// loads (x is dead afterwards) and non-temporal y stores.
// ---------------------------------------------------------------------------
__global__ __launch_bounds__(256) void ema_scan_norm_kernel(
    const float* __restrict__ x,
    const float* __restrict__ wm, const float* __restrict__ wsg,
    const float* __restrict__ h, const float* __restrict__ alpha_logit,
    const float* __restrict__ gamma, const float* __restrict__ beta,
    float* __restrict__ out, int B, int S, int d4_shift)
{
    const int tiles = S / TS;
    const int b     = (int)blockIdx.x / tiles;
    const int tile  = (int)blockIdx.x % tiles;
    const int s0    = tile * TS;
    const int tid   = (int)threadIdx.x;
    const int d4    = 1 << d4_shift;
    const int D     = d4 << 2;

    const float alpha = 1.0f / (1.0f + __expf(-alpha_logit[0]));
    const float oma   = 1.0f - alpha;
    const float l2a   = __log2f(alpha);
    const int   cut   = decay_cutoff(oma, l2a, S);

    const float* wmb = wm  + (size_t)b * S;
    const float* wsb = wsg + (size_t)b * S;

    __shared__ float sh_wm[4], sh_ws[4];
    __shared__ float sh_pm, sh_ps;
    __shared__ float sh_m[TS], sh_r[TS];

    // ---- Phase A: truncated weighted-prefix reduction over [0, min(s0,cut))
    const int m0 = (s0 < cut) ? s0 : cut;
    float lm = 0.f, ls = 0.f;
    for (int t = tid; t < m0; t += 256) {
        lm += wmb[t];
        ls += wsb[t];
    }
    lm = wave_reduce_sum(lm);
    ls = wave_reduce_sum(ls);
    if ((tid & 63) == 0) { sh_wm[tid >> 6] = lm; sh_ws[tid >> 6] = ls; }
    __syncthreads();
    if (tid == 0) {
        sh_pm = sh_wm[0] + sh_wm[1] + sh_wm[2] + sh_wm[3];
        sh_ps = sh_ws[0] + sh_ws[1] + sh_ws[2] + sh_ws[3];
    }
    __syncthreads();

    // ---- Phase B: wave 0 dual 32-lane scans (mu in lanes 0-31, sigma 32-63),
    //      zero-guarded past the decay cutoff (those rows were never written).
    if (tid < 64) {
        const int  r   = tid & 31;
        const bool isM = tid < 32;
        float v = 0.0f;
        if (s0 + r < cut) v = isM ? wmb[s0 + r] : wsb[s0 + r];
        #pragma unroll
        for (int off = 1; off < 32; off <<= 1) {
            float tv = __shfl_up(v, off, 32);
            if (r >= off) v += tv;
        }
        const float base = isM ? (alpha * h[b*2 + 0] + sh_pm)
                               : (alpha * h[b*2 + 1] + sh_ps);
        const float run = base + v;
        if (isM) sh_m[r] = run;
        else     sh_r[r] = 1.0f / fmaxf(run, EMA_EPS);
        if (s0 + TS == S && r == 31) {
            float* h_new = out + (size_t)B * S * D;
            if (isM) h_new[b*2 + 0] = run;
            else     h_new[b*2 + 1] = fmaxf(run, EMA_EPS);
        }
    }
    __syncthreads();

    // ---- Phase C: streaming normalize; nt loads (x dead after) + nt stores.
    //      Loads/stores go through the native ext-vector type v4f —
    //      __builtin_nontemporal_* rejects HIP_vector_type (struct) pointers.
    const size_t base = (size_t)(b * S + s0) << d4_shift;
    const v4f* xb = (const v4f*)x + base;
    v4f*       yb = (v4f*)out + base;
    const float4* g4 = (const float4*)gamma;
    const float4* b4 = (const float4*)beta;
    const int n4 = TS << d4_shift;
    #pragma unroll 4
    for (int i = tid; i < n4; i += 256) {
        const int r = i >> d4_shift;
        const int c = i & (d4 - 1);
        const float m  = sh_m[r];
        const float rs = sh_r[r];
        float4 g  = g4[c];
        float4 bt = b4[c];
        v4f xv = __builtin_nontemporal_load(&xb[i]);
        v4f yv;
        yv.x = (xv.x - m) * rs * g.x + bt.x;
        yv.y = (xv.y - m) * rs * g.y + bt.y;
        yv.z = (xv.z - m) * rs * g.z + bt.z;
        yv.w = (xv.w - m) * rs * g.w + bt.w;
        __builtin_nontemporal_store(yv, &yb[i]);
    }
}

extern "C" void kernel_launch(void* const* d_in, const int* in_sizes, int n_in,
                              void* d_out, int out_size, void* d_ws, size_t ws_size,
                              hipStream_t stream) {
    const float* x           = (const float*)d_in[0];
    const float* h           = (const float*)d_in[1];
    const float* gamma       = (const float*)d_in[2];
    const float* beta        = (const float*)d_in[3];
    const float* alpha_logit = (const float*)d_in[4];
    float* out = (float*)d_out;

    const int D     = in_sizes[2];          // 512
    const int B     = in_sizes[1] / 2;      // 8
    const int total = in_sizes[0];          // B*S*D
    const int S     = total / (B * D);      // 8192
    const int nrows = B * S;
    const int d4    = D / 4;
    const int d4_shift = __builtin_ctz(d4);

    float* wm_ws = (float*)d_ws;
    float* sg_ws = wm_ws + nrows;

    // K1: weighted stats for rows below the decay cutoff only.
    ema_stats_kernel<<<(nrows + 3) / 4, 256, 0, stream>>>(
        x, wm_ws, sg_ws, alpha_logit, nrows, S, d4);

    // K2: fused truncated-prefix + dual-scan + streaming normalize.
    ema_scan_norm_kernel<<<B * (S / TS), 256, 0, stream>>>(
        x, wm_ws, sg_ws, h, alpha_logit, gamma, beta, out, B, S, d4_shift);
}